// Round 14
// baseline (80.307 us; speedup 1.0000x reference)
//
#include <hip/hip_runtime.h>
#include <hip/hip_fp16.h>

#define N_NODES 100000
#define N_EDGES 1600000
#define F_IN    128
#define F_OUT   32

#define BKT_SHIFT  7
#define BKT_SIZE   128
#define NBKT       782          // ceil(100000/128)
#define BKT_STRIDE 2560         // mean 2046 per bucket, +11 sigma headroom
#define RP_STRIDE  132

#define BIN_THREADS 512
#define BIN_TILE    8192
#define EPT         16
#define NTILES      ((N_EDGES + BIN_TILE - 1) / BIN_TILE)  // 196

typedef _Float16 f16x8 __attribute__((ext_vector_type(8)));
typedef float    f32x4 __attribute__((ext_vector_type(4)));

#define WH_STRIDE 136   // halfs per W column (272 B -> conflict-free b128)

// Fused: blocks [0,NTILES) bin edges; blocks [NTILES, NTILES+NBKT) run the
// MFMA matmul (raw h, no dinv -> independent of binning). The x-stream and
// MFMA overlap the bin scatter's memory latency on the same device.
__global__ __launch_bounds__(512) void fused_bin_matmul_kernel(const int* __restrict__ ei,
                                                               int* __restrict__ gcur,
                                                               unsigned int* __restrict__ binned,
                                                               const float4* __restrict__ x4,
                                                               const float* __restrict__ W,
                                                               __half* __restrict__ hs) {
    __shared__ char pool[9216];
    int t = threadIdx.x;

    if (blockIdx.x < NTILES) {
        // ---------------- bin role ----------------
        int* cnt   = (int*)pool;           // NBKT
        int* gbase = cnt + NBKT;           // NBKT
        for (int b = t; b < NBKT; b += BIN_THREADS) cnt[b] = 0;
        __syncthreads();
        int ebase = blockIdx.x * BIN_TILE;
        unsigned int pk[EPT];
        int rk[EPT];
        short bkt[EPT];
#pragma unroll
        for (int k = 0; k < EPT; ++k) {
            int e = ebase + k * BIN_THREADS + t;
            if (e < N_EDGES) {
                int s = ei[e];
                int d = ei[N_EDGES + e];
                bkt[k] = (short)(d >> BKT_SHIFT);
                pk[k]  = (unsigned)s | ((unsigned)(d & (BKT_SIZE - 1)) << 25);
                rk[k]  = atomicAdd(&cnt[bkt[k]], 1);
            } else {
                bkt[k] = -1;
            }
        }
        __syncthreads();
        for (int b = t; b < NBKT; b += BIN_THREADS)
            if (cnt[b] > 0) gbase[b] = atomicAdd(&gcur[b], cnt[b]);
        __syncthreads();
#pragma unroll
        for (int k = 0; k < EPT; ++k) {
            if (bkt[k] >= 0) {
                int p = gbase[bkt[k]] + rk[k];
                if (p < BKT_STRIDE)
                    binned[(size_t)bkt[k] * BKT_STRIDE + p] = pk[k];
            }
        }
    } else {
        // ---------------- matmul role: hs = fp16(x @ W), raw ----------------
        _Float16* Wh = (_Float16*)pool;    // F_OUT * WH_STRIDE halfs = 8.7 KB
        int b = blockIdx.x - NTILES;
        {
            int col = t & 31, kb = (t >> 5) * 8;
            for (int u = 0; u < 8; ++u)
                Wh[col * WH_STRIDE + kb + u] = (_Float16)W[(kb + u) * F_OUT + col];
        }
        __syncthreads();

        int w = t >> 6, l = t & 63;
        int lr = l & 15, kg = l >> 4;                // A row lane, k-group
        int row = b * 128 + w * 16 + lr;
        const float4* xr = x4 + (size_t)row * 32;
        bool rok = row < N_NODES;

        f16x8 a[4];
#pragma unroll
        for (int ks = 0; ks < 4; ++ks) {
            float4 v0, v1;
            if (rok) {
                v0 = xr[ks * 8 + kg * 2];
                v1 = xr[ks * 8 + kg * 2 + 1];
            } else {
                v0 = make_float4(0, 0, 0, 0);
                v1 = v0;
            }
            f16x8 av;
            av[0] = (_Float16)v0.x; av[1] = (_Float16)v0.y;
            av[2] = (_Float16)v0.z; av[3] = (_Float16)v0.w;
            av[4] = (_Float16)v1.x; av[5] = (_Float16)v1.y;
            av[6] = (_Float16)v1.z; av[7] = (_Float16)v1.w;
            a[ks] = av;
        }

        f32x4 c0 = {0.f, 0.f, 0.f, 0.f}, c1 = {0.f, 0.f, 0.f, 0.f};
#pragma unroll
        for (int ks = 0; ks < 4; ++ks) {
            f16x8 b0 = *(const f16x8*)&Wh[lr * WH_STRIDE + ks * 32 + kg * 8];
            f16x8 b1 = *(const f16x8*)&Wh[(16 + lr) * WH_STRIDE + ks * 32 + kg * 8];
            c0 = __builtin_amdgcn_mfma_f32_16x16x32_f16(a[ks], b0, c0, 0, 0, 0);
            c1 = __builtin_amdgcn_mfma_f32_16x16x32_f16(a[ks], b1, c1, 0, 0, 0);
        }

        // D layout: col = lane&15, row = (lane>>4)*4 + i   [m89-verified]
        int lrow0 = w * 16 + kg * 4;
#pragma unroll
        for (int i = 0; i < 4; ++i) {
            int orow = b * 128 + lrow0 + i;
            if (orow < N_NODES) {
                hs[(size_t)orow * F_OUT + lr]      = (__half)c0[i];
                hs[(size_t)orow * F_OUT + 16 + lr] = (__half)c1[i];
            }
        }
    }
}

// One block per bucket: rank-capture counting sort of the bucket's edges into
// a global CSR (se_g + rowptr), plus dinv[node] = rsqrt(deg+1).
__global__ __launch_bounds__(256) void sort_kernel(const unsigned int* __restrict__ binned,
                                                   const int* __restrict__ gcur,
                                                   int* __restrict__ se_g,
                                                   int* __restrict__ rowptr,
                                                   float* __restrict__ dinv) {
    __shared__ int cnt[BKT_SIZE];
    __shared__ int sc[BKT_SIZE];
    __shared__ int rp[BKT_SIZE + 1];
    int t = threadIdx.x;
    int b = blockIdx.x;
    int ne = gcur[b];
    if (ne > BKT_STRIDE) ne = BKT_STRIDE;
    const unsigned int* eb = binned + (size_t)b * BKT_STRIDE;

    if (t < BKT_SIZE) cnt[t] = 0;
    __syncthreads();

    unsigned pk[10];
    int rk[10];
#pragma unroll
    for (int k = 0; k < 10; ++k) {
        int i = t + k * 256;
        pk[k] = (i < ne) ? eb[i] : 0xFFFFFFFFu;
    }
#pragma unroll
    for (int k = 0; k < 10; ++k) {
        rk[k] = -1;
        if (pk[k] != 0xFFFFFFFFu)
            rk[k] = atomicAdd(&cnt[pk[k] >> 25], 1);
    }
    __syncthreads();
    int v = (t < BKT_SIZE) ? cnt[t] : 0;
    if (t < BKT_SIZE) sc[t] = v;
    __syncthreads();
    for (int off = 1; off < BKT_SIZE; off <<= 1) {
        int add = (t < BKT_SIZE && t >= off) ? sc[t - off] : 0;
        __syncthreads();
        if (t < BKT_SIZE) sc[t] += add;
        __syncthreads();
    }
    if (t < BKT_SIZE) rp[t] = sc[t] - v;     // exclusive prefix
    if (t == 0) rp[BKT_SIZE] = ne;
    __syncthreads();

    int gnode = b * BKT_SIZE + t;
    if (t < BKT_SIZE && gnode < N_NODES)
        dinv[gnode] = rsqrtf((float)(cnt[t] + 1));   // +1 self loop
    if (t <= BKT_SIZE)
        rowptr[b * RP_STRIDE + t] = rp[t];

    int* se = se_g + (size_t)b * BKT_STRIDE;
#pragma unroll
    for (int k = 0; k < 10; ++k) {
        if (rk[k] >= 0) {
            int pos = rp[pk[k] >> 25] + rk[k];   // < ne <= BKT_STRIDE
            se[pos] = (int)(pk[k] & 0x1FFFFFF);
        }
    }
}

// Pure gather kernel, no LDS, no barriers. 4 blocks per bucket, 32 nodes each;
// 8 lanes/node x 8B half4 gathers with dinv[src] FMA, 8-deep unrolled.
__global__ __launch_bounds__(256) void aggregate_kernel(const int* __restrict__ se_g,
                                                        const int* __restrict__ rowptr,
                                                        const float* __restrict__ dinv,
                                                        const uint2* __restrict__ hs4,
                                                        const float* __restrict__ bias,
                                                        float* __restrict__ out) {
    int t = threadIdx.x;
    int b   = blockIdx.x >> 2;
    int sub = blockIdx.x & 3;
    int n = sub * 32 + (t >> 3);         // node within bucket
    int j4 = t & 7;                      // column quad
    int gnode = b * BKT_SIZE + n;
    if (gnode >= N_NODES) return;
    int beg = rowptr[b * RP_STRIDE + n];
    int end = rowptr[b * RP_STRIDE + n + 1];
    int deg = end - beg;
    const int* se = se_g + (size_t)b * BKT_STRIDE;

    float a0 = 0.f, a1 = 0.f, a2 = 0.f, a3 = 0.f;
    int p = beg;
    for (; p + 7 < end; p += 8) {        // 8 independent gathers in flight
        int s0 = se[p],     s1 = se[p + 1], s2 = se[p + 2], s3 = se[p + 3];
        int s4 = se[p + 4], s5 = se[p + 5], s6 = se[p + 6], s7 = se[p + 7];
        uint2 u0 = hs4[(size_t)s0 * 8 + j4]; float w0 = dinv[s0];
        uint2 u1 = hs4[(size_t)s1 * 8 + j4]; float w1 = dinv[s1];
        uint2 u2 = hs4[(size_t)s2 * 8 + j4]; float w2 = dinv[s2];
        uint2 u3 = hs4[(size_t)s3 * 8 + j4]; float w3 = dinv[s3];
        uint2 u4 = hs4[(size_t)s4 * 8 + j4]; float w4 = dinv[s4];
        uint2 u5 = hs4[(size_t)s5 * 8 + j4]; float w5 = dinv[s5];
        uint2 u6 = hs4[(size_t)s6 * 8 + j4]; float w6 = dinv[s6];
        uint2 u7 = hs4[(size_t)s7 * 8 + j4]; float w7 = dinv[s7];
#define FMA4(u, w) { \
        float2 f0 = __half22float2(*(__half2*)&(u).x); \
        float2 f1 = __half22float2(*(__half2*)&(u).y); \
        a0 = fmaf(f0.x, (w), a0); a1 = fmaf(f0.y, (w), a1); \
        a2 = fmaf(f1.x, (w), a2); a3 = fmaf(f1.y, (w), a3); }
        FMA4(u0, w0) FMA4(u1, w1) FMA4(u2, w2) FMA4(u3, w3)
        FMA4(u4, w4) FMA4(u5, w5) FMA4(u6, w6) FMA4(u7, w7)
    }
    for (; p + 1 < end; p += 2) {
        int s0 = se[p], s1 = se[p + 1];
        uint2 u0 = hs4[(size_t)s0 * 8 + j4]; float w0 = dinv[s0];
        uint2 u1 = hs4[(size_t)s1 * 8 + j4]; float w1 = dinv[s1];
        FMA4(u0, w0) FMA4(u1, w1)
    }
    if (p < end) {
        int s0 = se[p];
        uint2 u0 = hs4[(size_t)s0 * 8 + j4]; float w0 = dinv[s0];
        FMA4(u0, w0)
    }
#undef FMA4

    float dv = rsqrtf((float)(deg + 1));
    uint2 us = hs4[(size_t)gnode * 8 + j4];
    float2 s0 = __half22float2(*(__half2*)&us.x);
    float2 s1 = __half22float2(*(__half2*)&us.y);
    float4 bv = *(const float4*)&bias[j4 * 4];
    float4 o;
    o.x = bv.x + dv * (a0 + dv * s0.x);
    o.y = bv.y + dv * (a1 + dv * s0.y);
    o.z = bv.z + dv * (a2 + dv * s1.x);
    o.w = bv.w + dv * (a3 + dv * s1.y);
    *(float4*)&out[(size_t)gnode * F_OUT + j4 * 4] = o;
}

extern "C" void kernel_launch(void* const* d_in, const int* in_sizes, int n_in,
                              void* d_out, int out_size, void* d_ws, size_t ws_size,
                              hipStream_t stream) {
    const float* x  = (const float*)d_in[0];
    const int*   ei = (const int*)d_in[1];   // int32 on device
    const float* W  = (const float*)d_in[2];
    const float* b  = (const float*)d_in[3];
    float* out = (float*)d_out;

    int*          gcur   = (int*)d_ws;                                    // 1024
    unsigned int* binned = (unsigned int*)(gcur + 1024);                  // 8.0 MB
    int*          se_g   = (int*)(binned + (size_t)NBKT * BKT_STRIDE);    // 8.0 MB
    int*          rowptr = se_g + (size_t)NBKT * BKT_STRIDE;              // 413 KB
    float*        dinv   = (float*)(rowptr + NBKT * RP_STRIDE);           // 400 KB
    __half*       hs     = (__half*)(dinv + ((N_NODES + 3) & ~3));        // 6.4 MB

    hipMemsetAsync(gcur, 0, NBKT * sizeof(int), stream);

    fused_bin_matmul_kernel<<<NTILES + NBKT, 512, 0, stream>>>(ei, gcur, binned,
                                                               (const float4*)x, W, hs);

    sort_kernel<<<NBKT, 256, 0, stream>>>(binned, gcur, se_g, rowptr, dinv);

    aggregate_kernel<<<NBKT * 4, 256, 0, stream>>>(se_g, rowptr, dinv, (const uint2*)hs, b, out);
}

// Round 15
// 69.268 us; speedup vs baseline: 1.1594x; 1.1594x over previous
//
#include <hip/hip_runtime.h>
#include <hip/hip_fp16.h>

#define N_NODES 100000
#define N_EDGES 1600000
#define F_IN    128
#define F_OUT   32

#define BKT_SHIFT  7
#define BKT_SIZE   128
#define NBKT       782          // ceil(100000/128)
#define BKT_STRIDE 2560         // mean 2046 per bucket, +11 sigma headroom

#define BIN_THREADS 512
#define BIN_TILE    8192
#define EPT         (BIN_TILE / BIN_THREADS)               // 16
#define NTILES      ((N_EDGES + BIN_TILE - 1) / BIN_TILE)  // 196

#define AGG_SPLIT  2
#define SUB        64           // nodes per aggregate block
#define SUB_STRIDE 1408         // mean 1023/half-bucket, +12 sigma headroom

typedef _Float16 f16x8 __attribute__((ext_vector_type(8)));
typedef float    f32x4 __attribute__((ext_vector_type(4)));

// Bin edges by dst>>7 into 782 buckets. Rank-capture: one LDS atomic per edge
// gives both the histogram and the in-tile rank; 8192-edge tiles make
// same-bucket runs ~10 edges -> mostly full-line global writes.
__global__ __launch_bounds__(BIN_THREADS) void bin_kernel(const int* __restrict__ ei,
                                                          int* __restrict__ gcur,
                                                          unsigned int* __restrict__ binned) {
    __shared__ int cnt[NBKT], gbase[NBKT];
    int t = threadIdx.x;
    for (int b = t; b < NBKT; b += BIN_THREADS) cnt[b] = 0;
    __syncthreads();
    int ebase = blockIdx.x * BIN_TILE;
    unsigned int pk[EPT];
    int rk[EPT];
    short bkt[EPT];
#pragma unroll
    for (int k = 0; k < EPT; ++k) {
        int e = ebase + k * BIN_THREADS + t;
        if (e < N_EDGES) {
            int s = ei[e];
            int d = ei[N_EDGES + e];
            bkt[k] = (short)(d >> BKT_SHIFT);
            pk[k]  = (unsigned)s | ((unsigned)(d & (BKT_SIZE - 1)) << 25);
            rk[k]  = atomicAdd(&cnt[bkt[k]], 1);
        } else {
            bkt[k] = -1;
        }
    }
    __syncthreads();
    for (int b = t; b < NBKT; b += BIN_THREADS)
        if (cnt[b] > 0) gbase[b] = atomicAdd(&gcur[b], cnt[b]);
    __syncthreads();
#pragma unroll
    for (int k = 0; k < EPT; ++k) {
        if (bkt[k] >= 0) {
            int p = gbase[bkt[k]] + rk[k];
            if (p < BKT_STRIDE)
                binned[(size_t)bkt[k] * BKT_STRIDE + p] = pk[k];
        }
    }
}

// Fused: per-bucket degree histogram (-> dinv in LDS) + MFMA matmul for the
// bucket's 128 rows. hs = fp16( (x @ W) * dinv[row] ).  [R11-exact]
#define WH_STRIDE 136   // halfs per W column (272 B -> conflict-free b128)
__global__ __launch_bounds__(512) void matmul_kernel(const float4* __restrict__ x4,
                                                     const float* __restrict__ W,
                                                     const unsigned int* __restrict__ binned,
                                                     const int* __restrict__ gcur,
                                                     __half* __restrict__ hs) {
    __shared__ _Float16 Wh[F_OUT * WH_STRIDE];   // 8.7 KB, [col][k]
    __shared__ int cnt128[BKT_SIZE];
    __shared__ float dinvL[BKT_SIZE];
    int t = threadIdx.x;
    int b = blockIdx.x;

    if (t < BKT_SIZE) cnt128[t] = 0;
    {
        int col = t & 31, kb = (t >> 5) * 8;
        for (int u = 0; u < 8; ++u)
            Wh[col * WH_STRIDE + kb + u] = (_Float16)W[(kb + u) * F_OUT + col];
    }
    __syncthreads();

    int ne = gcur[b];
    if (ne > BKT_STRIDE) ne = BKT_STRIDE;
    const unsigned int* eb = binned + (size_t)b * BKT_STRIDE;
    for (int i = t; i < ne; i += 512)
        atomicAdd(&cnt128[eb[i] >> 25], 1);
    __syncthreads();
    if (t < BKT_SIZE) dinvL[t] = rsqrtf((float)(cnt128[t] + 1));  // +1 self loop
    __syncthreads();

    int w = t >> 6, l = t & 63;
    int lr = l & 15, kg = l >> 4;                // A row lane, k-group
    int row = b * 128 + w * 16 + lr;
    const float4* xr = x4 + (size_t)row * 32;
    bool rok = row < N_NODES;

    f16x8 a[4];
#pragma unroll
    for (int ks = 0; ks < 4; ++ks) {
        float4 v0, v1;
        if (rok) {
            v0 = xr[ks * 8 + kg * 2];
            v1 = xr[ks * 8 + kg * 2 + 1];
        } else {
            v0 = make_float4(0, 0, 0, 0);
            v1 = v0;
        }
        f16x8 av;
        av[0] = (_Float16)v0.x; av[1] = (_Float16)v0.y;
        av[2] = (_Float16)v0.z; av[3] = (_Float16)v0.w;
        av[4] = (_Float16)v1.x; av[5] = (_Float16)v1.y;
        av[6] = (_Float16)v1.z; av[7] = (_Float16)v1.w;
        a[ks] = av;
    }

    f32x4 c0 = {0.f, 0.f, 0.f, 0.f}, c1 = {0.f, 0.f, 0.f, 0.f};
#pragma unroll
    for (int ks = 0; ks < 4; ++ks) {
        f16x8 b0 = *(const f16x8*)&Wh[lr * WH_STRIDE + ks * 32 + kg * 8];
        f16x8 b1 = *(const f16x8*)&Wh[(16 + lr) * WH_STRIDE + ks * 32 + kg * 8];
        c0 = __builtin_amdgcn_mfma_f32_16x16x32_f16(a[ks], b0, c0, 0, 0, 0);
        c1 = __builtin_amdgcn_mfma_f32_16x16x32_f16(a[ks], b1, c1, 0, 0, 0);
    }

    // D layout: col = lane&15, row = (lane>>4)*4 + i   [m89-verified]
    int lrow0 = w * 16 + kg * 4;
#pragma unroll
    for (int i = 0; i < 4; ++i) {
        int orow = b * 128 + lrow0 + i;
        if (orow < N_NODES) {
            float dv = dinvL[lrow0 + i];
            hs[(size_t)orow * F_OUT + lr]      = (__half)(c0[i] * dv);
            hs[(size_t)orow * F_OUT + 16 + lr] = (__half)(c1[i] * dv);
        }
    }
}

__device__ inline void acc8(uint4 u, float* a) {
    float2 f0 = __half22float2(*(__half2*)&u.x);
    float2 f1 = __half22float2(*(__half2*)&u.y);
    float2 f2 = __half22float2(*(__half2*)&u.z);
    float2 f3 = __half22float2(*(__half2*)&u.w);
    a[0] += f0.x; a[1] += f0.y; a[2] += f1.x; a[3] += f1.y;
    a[4] += f2.x; a[5] += f2.y; a[6] += f3.x; a[7] += f3.y;
}

// 2 blocks per bucket, 64 nodes each (grid 1564). Rank-capture counting sort
// of the half-bucket's edges, then 4 lanes/node x 16B uint4 gathers, 8-deep
// (128 B in flight per lane).
__global__ __launch_bounds__(256) void aggregate_kernel(const unsigned int* __restrict__ binned,
                                                        const int* __restrict__ gcur,
                                                        const uint4* __restrict__ hs8,
                                                        const float* __restrict__ bias,
                                                        float* __restrict__ out) {
    __shared__ int cnt[SUB];
    __shared__ int sc[SUB];
    __shared__ int rp[SUB + 1];
    __shared__ int se[SUB_STRIDE];       // 5.5 KB
    int t = threadIdx.x;
    int b   = blockIdx.x >> 1;           // bucket
    int sub = blockIdx.x & 1;            // half of the bucket
    int ne = gcur[b];
    if (ne > BKT_STRIDE) ne = BKT_STRIDE;
    const unsigned int* eb = binned + (size_t)b * BKT_STRIDE;

    if (t < SUB) cnt[t] = 0;
    __syncthreads();

    unsigned pk[10];
    int rk[10];
#pragma unroll
    for (int k = 0; k < 10; ++k) {
        int i = t + k * 256;
        pk[k] = (i < ne) ? eb[i] : 0xFFFFFFFFu;
    }
#pragma unroll
    for (int k = 0; k < 10; ++k) {
        rk[k] = -1;
        if (pk[k] != 0xFFFFFFFFu) {
            int dl = (int)(pk[k] >> 25);
            if ((dl >> 6) == sub) rk[k] = atomicAdd(&cnt[dl & 63], 1);
        }
    }
    __syncthreads();
    int v = (t < SUB) ? cnt[t] : 0;
    if (t < SUB) sc[t] = v;
    __syncthreads();
    for (int off = 1; off < SUB; off <<= 1) {
        int add = (t < SUB && t >= off) ? sc[t - off] : 0;
        __syncthreads();
        if (t < SUB) sc[t] += add;
        __syncthreads();
    }
    if (t < SUB) {
        int ex = sc[t] - v;              // exclusive prefix
        rp[t] = (ex < SUB_STRIDE) ? ex : SUB_STRIDE;
    }
    if (t == 0) {
        int tot = sc[SUB - 1];
        rp[SUB] = (tot > SUB_STRIDE) ? SUB_STRIDE : tot;
    }
    __syncthreads();
#pragma unroll
    for (int k = 0; k < 10; ++k) {
        if (rk[k] >= 0) {
            int dl = (int)(pk[k] >> 25);
            int pos = rp[dl & 63] + rk[k];
            if (pos < SUB_STRIDE) se[pos] = (int)(pk[k] & 0x1FFFFFF);
        }
    }
    __syncthreads();

    int n = t >> 2, q = t & 3;           // 64 nodes x 4 lanes (8 cols/lane)
    int gnode = b * BKT_SIZE + sub * SUB + n;
    if (gnode >= N_NODES) return;
    int deg = cnt[n];
    int beg = rp[n];
    int end = rp[n + 1];
    if (beg + deg < end) end = beg + deg;
    float acc[8] = {0.f, 0.f, 0.f, 0.f, 0.f, 0.f, 0.f, 0.f};
    int p = beg;
    for (; p + 7 < end; p += 8) {        // 8 independent 16B gathers in flight
        uint4 u0 = hs8[(size_t)se[p]     * 4 + q];
        uint4 u1 = hs8[(size_t)se[p + 1] * 4 + q];
        uint4 u2 = hs8[(size_t)se[p + 2] * 4 + q];
        uint4 u3 = hs8[(size_t)se[p + 3] * 4 + q];
        uint4 u4 = hs8[(size_t)se[p + 4] * 4 + q];
        uint4 u5 = hs8[(size_t)se[p + 5] * 4 + q];
        uint4 u6 = hs8[(size_t)se[p + 6] * 4 + q];
        uint4 u7 = hs8[(size_t)se[p + 7] * 4 + q];
        acc8(u0, acc); acc8(u1, acc); acc8(u2, acc); acc8(u3, acc);
        acc8(u4, acc); acc8(u5, acc); acc8(u6, acc); acc8(u7, acc);
    }
    for (; p + 3 < end; p += 4) {
        uint4 u0 = hs8[(size_t)se[p]     * 4 + q];
        uint4 u1 = hs8[(size_t)se[p + 1] * 4 + q];
        uint4 u2 = hs8[(size_t)se[p + 2] * 4 + q];
        uint4 u3 = hs8[(size_t)se[p + 3] * 4 + q];
        acc8(u0, acc); acc8(u1, acc); acc8(u2, acc); acc8(u3, acc);
    }
    for (; p < end; ++p)
        acc8(hs8[(size_t)se[p] * 4 + q], acc);

    float dv = rsqrtf((float)(deg + 1));     // same value matmul folded for src
    uint4 us = hs8[(size_t)gnode * 4 + q];
    float selfv[8];
    {
        float2 f0 = __half22float2(*(__half2*)&us.x);
        float2 f1 = __half22float2(*(__half2*)&us.y);
        float2 f2 = __half22float2(*(__half2*)&us.z);
        float2 f3 = __half22float2(*(__half2*)&us.w);
        selfv[0] = f0.x; selfv[1] = f0.y; selfv[2] = f1.x; selfv[3] = f1.y;
        selfv[4] = f2.x; selfv[5] = f2.y; selfv[6] = f3.x; selfv[7] = f3.y;
    }
    float4 bv0 = *(const float4*)&bias[q * 8];
    float4 bv1 = *(const float4*)&bias[q * 8 + 4];
    float4 o0, o1;
    o0.x = bv0.x + dv * (acc[0] + selfv[0]);
    o0.y = bv0.y + dv * (acc[1] + selfv[1]);
    o0.z = bv0.z + dv * (acc[2] + selfv[2]);
    o0.w = bv0.w + dv * (acc[3] + selfv[3]);
    o1.x = bv1.x + dv * (acc[4] + selfv[4]);
    o1.y = bv1.y + dv * (acc[5] + selfv[5]);
    o1.z = bv1.z + dv * (acc[6] + selfv[6]);
    o1.w = bv1.w + dv * (acc[7] + selfv[7]);
    *(float4*)&out[(size_t)gnode * F_OUT + q * 8]     = o0;
    *(float4*)&out[(size_t)gnode * F_OUT + q * 8 + 4] = o1;
}

extern "C" void kernel_launch(void* const* d_in, const int* in_sizes, int n_in,
                              void* d_out, int out_size, void* d_ws, size_t ws_size,
                              hipStream_t stream) {
    const float* x  = (const float*)d_in[0];
    const int*   ei = (const int*)d_in[1];   // int32 on device
    const float* W  = (const float*)d_in[2];
    const float* b  = (const float*)d_in[3];
    float* out = (float*)d_out;

    int*          gcur   = (int*)d_ws;                       // pad to 1024
    unsigned int* binned = (unsigned int*)(gcur + 1024);     // NBKT*BKT_STRIDE ~8 MB
    __half*       hs     = (__half*)(binned + (size_t)NBKT * BKT_STRIDE);  // 6.4 MB

    hipMemsetAsync(gcur, 0, NBKT * sizeof(int), stream);

    bin_kernel<<<NTILES, BIN_THREADS, 0, stream>>>(ei, gcur, binned);

    matmul_kernel<<<NBKT, 512, 0, stream>>>((const float4*)x, W, binned, gcur, hs);

    aggregate_kernel<<<NBKT * AGG_SPLIT, 256, 0, stream>>>(binned, gcur, (const uint4*)hs, b, out);
}